// Round 7
// baseline (537.467 us; speedup 1.0000x reference)
//
#include <hip/hip_runtime.h>
#include <hip/hip_bf16.h>

// Problem constants (match reference)
#define NN 100000     // nodes
#define NE 1600000    // edges
#define HD 128        // feature/hidden dim
#define NG 512        // graphs
#define BN_EPS 1e-5f

#define GEMM_BLOCKS 1563          // ceil(NN/64)
#define NODES_PER_BLK 16          // final gather: nodes per block (work-stealing queue)
#define GATH_BLOCKS (NN / NODES_PER_BLK)   // 6250, exact

// ---- bin-sort CSR build params ----
#define BIN_SHIFT 8
#define NBIN 391                  // ceil(NN/256)
#define TILE 4096                 // edges per binning block
#define NBLK_BIN 391              // ceil(NE/TILE)

typedef __attribute__((ext_vector_type(8))) short short8;
typedef __attribute__((ext_vector_type(4))) float floatx4;

// ---- bf16 helpers (RNE) ----
__device__ __forceinline__ ushort f2bf(float f) {
    union { float f; uint u; } v; v.f = f;
    uint r = (v.u + 0x7FFF + ((v.u >> 16) & 1)) >> 16;
    return (ushort)r;
}
__device__ __forceinline__ float bflo(uint u) { union { uint u; float f; } v; v.u = u << 16; return v.f; }
__device__ __forceinline__ float bfhi(uint u) { union { uint u; float f; } v; v.u = u & 0xFFFF0000u; return v.f; }

// ---------------- fused prep: W transpose (blk<192) | BN affine (192-194) | graph counts (195-196) ----------------
__global__ void k_prep_all(const float* __restrict__ W1, const float* __restrict__ W2,
                           const float* __restrict__ W3,
                           ushort* __restrict__ Wt1, ushort* __restrict__ Wt2,
                           ushort* __restrict__ Wt3,
                           const float* __restrict__ b1, const float* __restrict__ g1,
                           const float* __restrict__ be1, const float* __restrict__ m1,
                           const float* __restrict__ v1,
                           const float* __restrict__ b2, const float* __restrict__ g2,
                           const float* __restrict__ be2, const float* __restrict__ m2,
                           const float* __restrict__ v2,
                           const float* __restrict__ b3, const float* __restrict__ g3,
                           const float* __restrict__ be3, const float* __restrict__ m3,
                           const float* __restrict__ v3,
                           float* scale1, float* shift1, float* scale2, float* shift2,
                           float* scale3, float* shift3,
                           const int* __restrict__ bat, float* __restrict__ invcnt,
                           float* __restrict__ out2d) {
    int blk = blockIdx.x, tid = threadIdx.x;
    if (blk < 192) {
        int w = blk >> 6;
        int i = (blk & 63) * 256 + tid;
        const float* W = (w == 0) ? W1 : (w == 1) ? W2 : W3;
        ushort* Wt = (w == 0) ? Wt1 : (w == 1) ? Wt2 : Wt3;
        int k = i >> 7, n = i & 127;
        Wt[n * 128 + k] = f2bf(W[i]);
    } else if (blk < 195) {
        if (tid < 128) {
            int l = blk - 192;
            const float *b, *g, *be, *m, *v;
            float *sc, *sh;
            if (l == 0)      { b = b1; g = g1; be = be1; m = m1; v = v1; sc = scale1; sh = shift1; }
            else if (l == 1) { b = b2; g = g2; be = be2; m = m2; v = v2; sc = scale2; sh = shift2; }
            else             { b = b3; g = g3; be = be3; m = m3; v = v3; sc = scale3; sh = shift3; }
            float s = g[tid] * rsqrtf(v[tid] + BN_EPS);
            sc[tid] = s;
            sh[tid] = (b[tid] - m[tid]) * s + be[tid];
        }
    } else {
        int g = (blk - 195) * 256 + tid;
        if (g < NG) {
            int lo = 0, hi = NN;
            while (lo < hi) { int mid = (lo + hi) >> 1; if (bat[mid] < g) lo = mid + 1; else hi = mid; }
            int lo2 = lo, hi2 = NN;
            while (lo2 < hi2) { int mid = (lo2 + hi2) >> 1; if (bat[mid] < g + 1) lo2 = mid + 1; else hi2 = mid; }
            int cnt = lo2 - lo;
            invcnt[g] = 1.f / fmaxf((float)cnt, 1.f);
#pragma unroll
            for (int i = 0; i < 8; ++i) out2d[g * 8 + i] = 0.f;
        }
    }
}

// ---------------- fused: GEMM1 (fp32 x @ Wt1 -> unscaled bf16 hs)  ||  bin histogram (LDS, no global atomics) ----------------
__launch_bounds__(256)
__global__ void k_fused1(const float* __restrict__ x, const ushort* __restrict__ Wt,
                         ushort* __restrict__ hs,
                         const int* __restrict__ dst, int* __restrict__ L) {
    __shared__ int lh[NBIN];
    const int tid = threadIdx.x;
    if (blockIdx.x >= GEMM_BLOCKS) {
        // ---- bin histogram role: 391 blocks, 4096 edges each ----
        int blk = blockIdx.x - GEMM_BLOCKS;
        for (int i = tid; i < NBIN; i += 256) lh[i] = 0;
        __syncthreads();
        long base = (long)blk * TILE;
#pragma unroll 4
        for (int i = 0; i < TILE / 256; ++i) {
            long e = base + i * 256 + tid;
            if (e < NE) atomicAdd(&lh[dst[e] >> BIN_SHIFT], 1);
        }
        __syncthreads();
        for (int i = tid; i < NBIN; i += 256) L[i * NBLK_BIN + blk] = lh[i];
        return;
    }
    // ---- GEMM role: 4 waves, 64 rows, B-frags straight from global (L1-resident 32 KB) ----
    const int wave = tid >> 6, lane = tid & 63;
    const int m = lane & 15, kg = lane >> 4;
    const long row0 = (long)blockIdx.x * 64 + wave * 16;

    long arow = row0 + m;
    long arc = arow < NN ? arow : (NN - 1);
    const float* xf = x + arc * 128;
    short8 a[4];
#pragma unroll
    for (int s = 0; s < 4; ++s) {
        float4 f0 = *(const float4*)(xf + s * 32 + kg * 8);
        float4 f1 = *(const float4*)(xf + s * 32 + kg * 8 + 4);
        short8 t;
        t[0] = (short)f2bf(f0.x); t[1] = (short)f2bf(f0.y);
        t[2] = (short)f2bf(f0.z); t[3] = (short)f2bf(f0.w);
        t[4] = (short)f2bf(f1.x); t[5] = (short)f2bf(f1.y);
        t[6] = (short)f2bf(f1.z); t[7] = (short)f2bf(f1.w);
        a[s] = t;
    }

    floatx4 acc[8];
#pragma unroll
    for (int ct = 0; ct < 8; ++ct) acc[ct] = (floatx4){0.f, 0.f, 0.f, 0.f};

#pragma unroll
    for (int s = 0; s < 4; ++s) {
#pragma unroll
        for (int ct = 0; ct < 8; ++ct) {
            short8 b = *(const short8*)(Wt + (ct * 16 + m) * 128 + s * 32 + kg * 8);
            acc[ct] = __builtin_amdgcn_mfma_f32_16x16x32_bf16(a[s], b, acc[ct], 0, 0, 0);
        }
    }

#pragma unroll
    for (int r = 0; r < 4; ++r) {
        long orow = row0 + kg * 4 + r;
        if (orow < NN) {
#pragma unroll
            for (int ct = 0; ct < 8; ++ct)
                hs[orow * 128 + ct * 16 + m] = f2bf(acc[ct][r]);   // unscaled
        }
    }
}

// ---------------- scanA: per-bin exclusive scan across blocks (one block per bin) ----------------
__global__ void k_scanA(int* __restrict__ L, int* __restrict__ binTot) {
    __shared__ int s[512];
    int b = blockIdx.x, t = threadIdx.x;   // 512 threads
    int v = (t < NBLK_BIN) ? L[b * NBLK_BIN + t] : 0;
    s[t] = v;
    __syncthreads();
    for (int o = 1; o < 512; o <<= 1) {
        int x = (t >= o) ? s[t - o] : 0;
        __syncthreads();
        s[t] += x;
        __syncthreads();
    }
    if (t < NBLK_BIN) L[b * NBLK_BIN + t] = s[t] - v;   // exclusive within bin
    if (t == 511) binTot[b] = s[511];
}

// ---------------- scanB: exclusive scan over bin totals -> bin edge bases ----------------
__global__ void k_scanB(const int* __restrict__ binTot, int* __restrict__ bin_ebase,
                        int* __restrict__ rs) {
    __shared__ int s[512];
    int t = threadIdx.x;
    int v = (t < NBIN) ? binTot[t] : 0;
    s[t] = v;
    __syncthreads();
    for (int o = 1; o < 512; o <<= 1) {
        int x = (t >= o) ? s[t - o] : 0;
        __syncthreads();
        s[t] += x;
        __syncthreads();
    }
    if (t < NBIN) bin_ebase[t] = s[t] - v;
    if (t == 0) { bin_ebase[NBIN] = NE; rs[NN] = NE; }
}

// ---------------- C: scatter edges into bin-grouped order (LDS cursors only) ----------------
__launch_bounds__(256)
__global__ void k_binscatter(const int* __restrict__ src, const int* __restrict__ dst,
                             const int* __restrict__ L, const int* __restrict__ bin_ebase,
                             uint* __restrict__ bpack) {
    __shared__ int off[NBIN];
    int t = threadIdx.x, blk = blockIdx.x;
    for (int i = t; i < NBIN; i += 256) off[i] = L[i * NBLK_BIN + blk] + bin_ebase[i];
    __syncthreads();
    long base = (long)blk * TILE;
#pragma unroll 4
    for (int i = 0; i < TILE / 256; ++i) {
        long e = base + i * 256 + t;
        if (e < NE) {
            int d = dst[e];
            int p = atomicAdd(&off[d >> BIN_SHIFT], 1);
            bpack[p] = (uint)src[e] | ((uint)(d & 255) << 24);   // src<2^17, local node in top 8
        }
    }
}

// ---------------- D: per-bin exact CSR + rs + dinv (all LDS) ----------------
__launch_bounds__(256)
__global__ void k_bincsr(const uint* __restrict__ bpack, const int* __restrict__ bin_ebase,
                         int* __restrict__ rs, float* __restrict__ dinv,
                         int* __restrict__ csr) {
    __shared__ int cnt[256];
    __shared__ int sc[256];
    __shared__ int run[256];
    int t = threadIdx.x, b = blockIdx.x;
    int e0 = bin_ebase[b], e1 = bin_ebase[b + 1];
    cnt[t] = 0;
    __syncthreads();
    for (int e = e0 + t; e < e1; e += 256) atomicAdd(&cnt[bpack[e] >> 24], 1);
    __syncthreads();
    int c = cnt[t];
    sc[t] = c;
    __syncthreads();
    for (int o = 1; o < 256; o <<= 1) {
        int x = (t >= o) ? sc[t - o] : 0;
        __syncthreads();
        sc[t] += x;
        __syncthreads();
    }
    int excl = sc[t] - c;
    int node = (b << BIN_SHIFT) + t;
    if (node < NN) {
        rs[node] = e0 + excl;
        dinv[node] = rsqrtf((float)(c + 1));   // +1 self-loop
    }
    run[t] = e0 + excl;
    __syncthreads();
    for (int e = e0 + t; e < e1; e += 256) {
        uint u = bpack[e];
        int p = atomicAdd(&run[u >> 24], 1);
        csr[p] = (int)(u & 0xFFFFFFu);
    }
}

// ---------------- FUSED gather+BN+ReLU+GEMM: one block = 64 nodes = one GEMM row-tile ----------------
// Phase 1: 4 waves work-steal the block's 64 node-gathers (LDS counter), each
// producing a BN+ReLU'd bf16 row into the LDS A-tile (stride 136: 2-way-free
// for both 16B row writes and MFMA frag reads).
// Phase 2: __syncthreads, then k_fused1-style MFMA (B-frags straight from
// global Wt, L1-resident 32 KB) with dinv-scaled epilogue -> hout.
// This deletes the standalone gemm kernel and the xbuf round-trip (2x25.6 MB).
// SCALE_SRC: input hs rows are unscaled (layer 1) -> apply dinv[s] per edge.
template <bool SCALE_SRC>
__launch_bounds__(256)
__global__ void k_gath_gemm(const ushort* __restrict__ hs, const int* __restrict__ rs,
                            const int* __restrict__ csr, const float* __restrict__ dinv,
                            const float* __restrict__ scale, const float* __restrict__ shift,
                            const ushort* __restrict__ Wt, ushort* __restrict__ hout) {
    __shared__ ushort A[64 * 136];
    __shared__ int nextn;
    const int tid = threadIdx.x;
    if (tid == 0) nextn = 0;
    __syncthreads();
    const int lane = tid & 63;
    const int sub = lane >> 4;
    const int c0 = (lane & 15) * 8;
    const int base = blockIdx.x * 64;

    for (int it = 0; it <= 64; ++it) {
        int myn = 0;
        if (lane == 0) myn = atomicAdd(&nextn, 1);
        myn = __shfl(myn, 0);
        if (myn >= 64) break;
        const int d = base + myn;
        if (d >= NN) {   // tail rows: zero-fill for tile hygiene (never stored)
            if (sub == 0) { uint4 z = {0u, 0u, 0u, 0u}; *(uint4*)&A[myn * 136 + c0] = z; }
            continue;
        }

        const int e0 = rs[d], e1 = rs[d + 1];
        const float dd = dinv[d];

        float a0 = 0.f, a1 = 0.f, a2 = 0.f, a3 = 0.f,
              a4 = 0.f, a5 = 0.f, a6 = 0.f, a7 = 0.f;

        if (sub == 0) {   // self-loop term
            uint4 sv = *(const uint4*)(hs + (long)d * 128 + c0);
            float w = SCALE_SRC ? dd : 1.0f;
            a0 = w * bflo(sv.x); a1 = w * bfhi(sv.x);
            a2 = w * bflo(sv.y); a3 = w * bfhi(sv.y);
            a4 = w * bflo(sv.z); a5 = w * bfhi(sv.z);
            a6 = w * bflo(sv.w); a7 = w * bfhi(sv.w);
        }

        int j = e0 + sub;
        // ---- quad loop: rows j, j+4, j+8, j+12; next quad's indices prefetched ----
        int s0 = 0, s1 = 0, s2 = 0, s3 = 0;
        bool have = (j + 12 < e1);
        if (have) { s0 = csr[j]; s1 = csr[j + 4]; s2 = csr[j + 8]; s3 = csr[j + 12]; }
        while (have) {
            int jn = j + 16;
            bool nxt = (jn + 12 < e1);
            int n0 = 0, n1 = 0, n2 = 0, n3 = 0;
            if (nxt) { n0 = csr[jn]; n1 = csr[jn + 4]; n2 = csr[jn + 8]; n3 = csr[jn + 12]; }
            float w0 = 1.f, w1 = 1.f, w2 = 1.f, w3 = 1.f;
            if (SCALE_SRC) { w0 = dinv[s0]; w1 = dinv[s1]; w2 = dinv[s2]; w3 = dinv[s3]; }
            uint4 v0 = *(const uint4*)(hs + (long)s0 * 128 + c0);
            uint4 v1 = *(const uint4*)(hs + (long)s1 * 128 + c0);
            uint4 v2 = *(const uint4*)(hs + (long)s2 * 128 + c0);
            uint4 v3 = *(const uint4*)(hs + (long)s3 * 128 + c0);
            a0 += w0 * bflo(v0.x) + w1 * bflo(v1.x) + w2 * bflo(v2.x) + w3 * bflo(v3.x);
            a1 += w0 * bfhi(v0.x) + w1 * bfhi(v1.x) + w2 * bfhi(v2.x) + w3 * bfhi(v3.x);
            a2 += w0 * bflo(v0.y) + w1 * bflo(v1.y) + w2 * bflo(v2.y) + w3 * bflo(v3.y);
            a3 += w0 * bfhi(v0.y) + w1 * bfhi(v1.y) + w2 * bfhi(v2.y) + w3 * bfhi(v3.y);
            a4 += w0 * bflo(v0.z) + w1 * bflo(v1.z) + w2 * bflo(v2.z) + w3 * bflo(v3.z);
            a5 += w0 * bfhi(v0.z) + w1 * bfhi(v1.z) + w2 * bfhi(v2.z) + w3 * bfhi(v3.z);
            a6 += w0 * bflo(v0.w) + w1 * bflo(v1.w) + w2 * bflo(v2.w) + w3 * bflo(v3.w);
            a7 += w0 * bfhi(v0.w) + w1 * bfhi(v1.w) + w2 * bfhi(v2.w) + w3 * bfhi(v3.w);
            j = jn; s0 = n0; s1 = n1; s2 = n2; s3 = n3; have = nxt;
        }
        // ---- tail: up to 3 rows (j, j+4, j+8), all loads issued together ----
        if (j < e1) {
            bool b1 = (j + 4) < e1, b2 = (j + 8) < e1;
            int t0 = csr[j];
            int t1 = b1 ? csr[j + 4] : t0;
            int t2 = b2 ? csr[j + 8] : t0;
            float w0 = SCALE_SRC ? dinv[t0] : 1.f;
            float w1 = b1 ? (SCALE_SRC ? dinv[t1] : 1.f) : 0.f;
            float w2 = b2 ? (SCALE_SRC ? dinv[t2] : 1.f) : 0.f;
            uint4 v0 = *(const uint4*)(hs + (long)t0 * 128 + c0);
            uint4 v1 = *(const uint4*)(hs + (long)t1 * 128 + c0);
            uint4 v2 = *(const uint4*)(hs + (long)t2 * 128 + c0);
            a0 += w0 * bflo(v0.x) + w1 * bflo(v1.x) + w2 * bflo(v2.x);
            a1 += w0 * bfhi(v0.x) + w1 * bfhi(v1.x) + w2 * bfhi(v2.x);
            a2 += w0 * bflo(v0.y) + w1 * bflo(v1.y) + w2 * bflo(v2.y);
            a3 += w0 * bfhi(v0.y) + w1 * bfhi(v1.y) + w2 * bfhi(v2.y);
            a4 += w0 * bflo(v0.z) + w1 * bflo(v1.z) + w2 * bflo(v2.z);
            a5 += w0 * bfhi(v0.z) + w1 * bfhi(v1.z) + w2 * bfhi(v2.z);
            a6 += w0 * bflo(v0.w) + w1 * bflo(v1.w) + w2 * bflo(v2.w);
            a7 += w0 * bfhi(v0.w) + w1 * bfhi(v1.w) + w2 * bfhi(v2.w);
        }

        // reduce across the 4 edge slots (lanes differing in bits 4,5)
        a0 += __shfl_xor(a0, 16); a1 += __shfl_xor(a1, 16);
        a2 += __shfl_xor(a2, 16); a3 += __shfl_xor(a3, 16);
        a4 += __shfl_xor(a4, 16); a5 += __shfl_xor(a5, 16);
        a6 += __shfl_xor(a6, 16); a7 += __shfl_xor(a7, 16);
        a0 += __shfl_xor(a0, 32); a1 += __shfl_xor(a1, 32);
        a2 += __shfl_xor(a2, 32); a3 += __shfl_xor(a3, 32);
        a4 += __shfl_xor(a4, 32); a5 += __shfl_xor(a5, 32);
        a6 += __shfl_xor(a6, 32); a7 += __shfl_xor(a7, 32);

        if (sub == 0) {
            float4 sca = *(const float4*)(scale + c0);
            float4 scb = *(const float4*)(scale + c0 + 4);
            float4 sha = *(const float4*)(shift + c0);
            float4 shb = *(const float4*)(shift + c0 + 4);
            float r0 = fmaxf(dd * a0 * sca.x + sha.x, 0.f);
            float r1 = fmaxf(dd * a1 * sca.y + sha.y, 0.f);
            float r2 = fmaxf(dd * a2 * sca.z + sha.z, 0.f);
            float r3 = fmaxf(dd * a3 * sca.w + sha.w, 0.f);
            float r4 = fmaxf(dd * a4 * scb.x + shb.x, 0.f);
            float r5 = fmaxf(dd * a5 * scb.y + shb.y, 0.f);
            float r6 = fmaxf(dd * a6 * scb.z + shb.z, 0.f);
            float r7 = fmaxf(dd * a7 * scb.w + shb.w, 0.f);
            uint4 o;
            o.x = (uint)f2bf(r0) | ((uint)f2bf(r1) << 16);
            o.y = (uint)f2bf(r2) | ((uint)f2bf(r3) << 16);
            o.z = (uint)f2bf(r4) | ((uint)f2bf(r5) << 16);
            o.w = (uint)f2bf(r6) | ((uint)f2bf(r7) << 16);
            *(uint4*)&A[myn * 136 + c0] = o;
        }
    }
    __syncthreads();

    // ---- GEMM phase: A(64x128 LDS) @ Wt -> hout, dinv-scaled rows ----
    const int wave = tid >> 6;
    const int m = lane & 15, kg = lane >> 4;
    const long row0 = (long)base + wave * 16;

    short8 a[4];
#pragma unroll
    for (int s = 0; s < 4; ++s)
        a[s] = *(const short8*)&A[(wave * 16 + m) * 136 + s * 32 + kg * 8];

    floatx4 acc[8];
#pragma unroll
    for (int ct = 0; ct < 8; ++ct) acc[ct] = (floatx4){0.f, 0.f, 0.f, 0.f};

#pragma unroll
    for (int s = 0; s < 4; ++s) {
#pragma unroll
        for (int ct = 0; ct < 8; ++ct) {
            short8 b = *(const short8*)(Wt + (ct * 16 + m) * 128 + s * 32 + kg * 8);
            acc[ct] = __builtin_amdgcn_mfma_f32_16x16x32_bf16(a[s], b, acc[ct], 0, 0, 0);
        }
    }

#pragma unroll
    for (int r = 0; r < 4; ++r) {
        long orow = row0 + kg * 4 + r;
        if (orow < NN) {
            float dd2 = dinv[orow];
#pragma unroll
            for (int ct = 0; ct < 8; ++ct)
                hout[orow * 128 + ct * 16 + m] = f2bf(acc[ct][r] * dd2);
        }
    }
}

// ---------------- final gather + BN + ReLU + pool + linear (work-stealing, proven R6) ----------------
__launch_bounds__(256)
__global__ void k_gather_pool(const ushort* __restrict__ hs, const int* __restrict__ rs,
                              const int* __restrict__ csr, const float* __restrict__ dinv,
                              const float* __restrict__ scale, const float* __restrict__ shift,
                              const int* __restrict__ bat, const float* __restrict__ invcnt,
                              const float* __restrict__ Wl, float* __restrict__ out2d) {
    __shared__ int nextn;
    const int tid = threadIdx.x;
    if (tid == 0) nextn = 0;
    __syncthreads();
    const int lane = tid & 63;
    const int sub = lane >> 4;
    const int c0 = (lane & 15) * 8;
    const int base = blockIdx.x * NODES_PER_BLK;

    for (int it = 0; it <= NODES_PER_BLK; ++it) {
        int myn = 0;
        if (lane == 0) myn = atomicAdd(&nextn, 1);
        myn = __shfl(myn, 0);
        if (myn >= NODES_PER_BLK) break;
        const int d = base + myn;

        const int e0 = rs[d], e1 = rs[d + 1];
        const float dd = dinv[d];

        float a0 = 0.f, a1 = 0.f, a2 = 0.f, a3 = 0.f,
              a4 = 0.f, a5 = 0.f, a6 = 0.f, a7 = 0.f;

        if (sub == 0) {   // self-loop term (hs pre-scaled)
            uint4 sv = *(const uint4*)(hs + (long)d * 128 + c0);
            a0 = bflo(sv.x); a1 = bfhi(sv.x);
            a2 = bflo(sv.y); a3 = bfhi(sv.y);
            a4 = bflo(sv.z); a5 = bfhi(sv.z);
            a6 = bflo(sv.w); a7 = bfhi(sv.w);
        }

        int j = e0 + sub;
        int s0 = 0, s1 = 0, s2 = 0, s3 = 0;
        bool have = (j + 12 < e1);
        if (have) { s0 = csr[j]; s1 = csr[j + 4]; s2 = csr[j + 8]; s3 = csr[j + 12]; }
        while (have) {
            int jn = j + 16;
            bool nxt = (jn + 12 < e1);
            int n0 = 0, n1 = 0, n2 = 0, n3 = 0;
            if (nxt) { n0 = csr[jn]; n1 = csr[jn + 4]; n2 = csr[jn + 8]; n3 = csr[jn + 12]; }
            uint4 v0 = *(const uint4*)(hs + (long)s0 * 128 + c0);
            uint4 v1 = *(const uint4*)(hs + (long)s1 * 128 + c0);
            uint4 v2 = *(const uint4*)(hs + (long)s2 * 128 + c0);
            uint4 v3 = *(const uint4*)(hs + (long)s3 * 128 + c0);
            a0 += bflo(v0.x) + bflo(v1.x) + bflo(v2.x) + bflo(v3.x);
            a1 += bfhi(v0.x) + bfhi(v1.x) + bfhi(v2.x) + bfhi(v3.x);
            a2 += bflo(v0.y) + bflo(v1.y) + bflo(v2.y) + bflo(v3.y);
            a3 += bfhi(v0.y) + bfhi(v1.y) + bfhi(v2.y) + bfhi(v3.y);
            a4 += bflo(v0.z) + bflo(v1.z) + bflo(v2.z) + bflo(v3.z);
            a5 += bfhi(v0.z) + bfhi(v1.z) + bfhi(v2.z) + bfhi(v3.z);
            a6 += bflo(v0.w) + bflo(v1.w) + bflo(v2.w) + bflo(v3.w);
            a7 += bfhi(v0.w) + bfhi(v1.w) + bfhi(v2.w) + bfhi(v3.w);
            j = jn; s0 = n0; s1 = n1; s2 = n2; s3 = n3; have = nxt;
        }
        if (j < e1) {
            bool b1 = (j + 4) < e1, b2 = (j + 8) < e1;
            int t0 = csr[j];
            int t1 = b1 ? csr[j + 4] : t0;
            int t2 = b2 ? csr[j + 8] : t0;
            float w1 = b1 ? 1.f : 0.f;
            float w2 = b2 ? 1.f : 0.f;
            uint4 v0 = *(const uint4*)(hs + (long)t0 * 128 + c0);
            uint4 v1 = *(const uint4*)(hs + (long)t1 * 128 + c0);
            uint4 v2 = *(const uint4*)(hs + (long)t2 * 128 + c0);
            a0 += bflo(v0.x) + w1 * bflo(v1.x) + w2 * bflo(v2.x);
            a1 += bfhi(v0.x) + w1 * bfhi(v1.x) + w2 * bfhi(v2.x);
            a2 += bflo(v0.y) + w1 * bflo(v1.y) + w2 * bflo(v2.y);
            a3 += bfhi(v0.y) + w1 * bfhi(v1.y) + w2 * bfhi(v2.y);
            a4 += bflo(v0.z) + w1 * bflo(v1.z) + w2 * bflo(v2.z);
            a5 += bfhi(v0.z) + w1 * bfhi(v1.z) + w2 * bfhi(v2.z);
            a6 += bflo(v0.w) + w1 * bflo(v1.w) + w2 * bflo(v2.w);
            a7 += bfhi(v0.w) + w1 * bfhi(v1.w) + w2 * bfhi(v2.w);
        }

        a0 += __shfl_xor(a0, 16); a1 += __shfl_xor(a1, 16);
        a2 += __shfl_xor(a2, 16); a3 += __shfl_xor(a3, 16);
        a4 += __shfl_xor(a4, 16); a5 += __shfl_xor(a5, 16);
        a6 += __shfl_xor(a6, 16); a7 += __shfl_xor(a7, 16);
        a0 += __shfl_xor(a0, 32); a1 += __shfl_xor(a1, 32);
        a2 += __shfl_xor(a2, 32); a3 += __shfl_xor(a3, 32);
        a4 += __shfl_xor(a4, 32); a5 += __shfl_xor(a5, 32);
        a6 += __shfl_xor(a6, 32); a7 += __shfl_xor(a7, 32);

        float pd = 0.f;
        if (sub == 0) {
            float4 sca = *(const float4*)(scale + c0);
            float4 scb = *(const float4*)(scale + c0 + 4);
            float4 sha = *(const float4*)(shift + c0);
            float4 shb = *(const float4*)(shift + c0 + 4);
            float r0 = fmaxf(dd * a0 * sca.x + sha.x, 0.f);
            float r1 = fmaxf(dd * a1 * sca.y + sha.y, 0.f);
            float r2 = fmaxf(dd * a2 * sca.z + sha.z, 0.f);
            float r3 = fmaxf(dd * a3 * sca.w + sha.w, 0.f);
            float r4 = fmaxf(dd * a4 * scb.x + shb.x, 0.f);
            float r5 = fmaxf(dd * a5 * scb.y + shb.y, 0.f);
            float r6 = fmaxf(dd * a6 * scb.z + shb.z, 0.f);
            float r7 = fmaxf(dd * a7 * scb.w + shb.w, 0.f);
            float4 wa = *(const float4*)(Wl + c0);
            float4 wb = *(const float4*)(Wl + c0 + 4);
            pd = r0 * wa.x + r1 * wa.y + r2 * wa.z + r3 * wa.w +
                 r4 * wb.x + r5 * wb.y + r6 * wb.z + r7 * wb.w;
        }
        pd += __shfl_xor(pd, 1);
        pd += __shfl_xor(pd, 2);
        pd += __shfl_xor(pd, 4);
        pd += __shfl_xor(pd, 8);
        if (lane == 0) {
            int g = bat[d];
            atomicAdd(&out2d[g * 8 + (d & 7)], pd * invcnt[g]);
        }
    }
}

// ---------------- finalize: out[g] = bl + sum of 8 slots ----------------
__global__ void k_final(const float* __restrict__ out2d, const float* __restrict__ bl,
                        float* __restrict__ out) {
    int g = blockIdx.x * 256 + threadIdx.x;
    if (g >= NG) return;
    float s = bl[0];
#pragma unroll
    for (int i = 0; i < 8; ++i) s += out2d[g * 8 + i];
    out[g] = s;
}

// ---------------- launch ----------------
extern "C" void kernel_launch(void* const* d_in, const int* in_sizes, int n_in,
                              void* d_out, int out_size, void* d_ws, size_t ws_size,
                              hipStream_t stream) {
    const float* x   = (const float*)d_in[0];
    const int*   ei  = (const int*)d_in[1];
    const int*   bat = (const int*)d_in[2];
    const float* W1  = (const float*)d_in[3];
    const float* b1  = (const float*)d_in[4];
    const float* g1  = (const float*)d_in[5];
    const float* be1 = (const float*)d_in[6];
    const float* m1  = (const float*)d_in[7];
    const float* v1  = (const float*)d_in[8];
    const float* W2  = (const float*)d_in[9];
    const float* b2  = (const float*)d_in[10];
    const float* g2  = (const float*)d_in[11];
    const float* be2 = (const float*)d_in[12];
    const float* m2  = (const float*)d_in[13];
    const float* v2  = (const float*)d_in[14];
    const float* W3  = (const float*)d_in[15];
    const float* b3  = (const float*)d_in[16];
    const float* g3  = (const float*)d_in[17];
    const float* be3 = (const float*)d_in[18];
    const float* m3  = (const float*)d_in[19];
    const float* v3  = (const float*)d_in[20];
    const float* Wl  = (const float*)d_in[21];
    const float* bl  = (const float*)d_in[22];
    float* out = (float*)d_out;

    const int* srcp = ei;        // edge_index[0]
    const int* dstp = ei + NE;   // edge_index[1]

    // ---- workspace layout ----
    char* ws = (char*)d_ws;
    size_t off = 0;
    auto alloc = [&](size_t bytes) { char* p = ws + off; off += (bytes + 255) & ~255ULL; return p; };
    float*  dinv     = (float*) alloc(NN * 4);
    int*    rs       = (int*)   alloc((NN + 1) * 4);
    int*    L        = (int*)   alloc((size_t)NBIN * NBLK_BIN * 4);   // block-bin table, 612 KB
    int*    binTot   = (int*)   alloc((NBIN + 1) * 4);
    int*    bin_ebase= (int*)   alloc((NBIN + 1) * 4);
    uint*   bpack    = (uint*)  alloc((size_t)NE * 4);   // 6.4 MB (bin-grouped edges)
    int*    csr      = (int*)   alloc((size_t)NE * 4);   // 6.4 MB
    float*  scale1 = (float*) alloc(HD * 4);
    float*  shift1 = (float*) alloc(HD * 4);
    float*  scale2 = (float*) alloc(HD * 4);
    float*  shift2 = (float*) alloc(HD * 4);
    float*  scale3 = (float*) alloc(HD * 4);
    float*  shift3 = (float*) alloc(HD * 4);
    float*  invcnt = (float*) alloc(NG * 4);
    float*  out2d  = (float*) alloc(NG * 8 * 4);
    ushort* Wt1    = (ushort*)alloc(128 * 128 * 2);    // 32 KB
    ushort* Wt2    = (ushort*)alloc(128 * 128 * 2);
    ushort* Wt3    = (ushort*)alloc(128 * 128 * 2);
    ushort* hs     = (ushort*)alloc((size_t)NN * HD * 2);   // 25.6 MB
    ushort* xbuf   = (ushort*)alloc((size_t)NN * HD * 2);   // 25.6 MB

    // ---- prep: W transpose + BN affine + graph inv-counts (one launch) ----
    k_prep_all<<<197, 256, 0, stream>>>(W1, W2, W3, Wt1, Wt2, Wt3,
                                        b1, g1, be1, m1, v1, b2, g2, be2, m2, v2,
                                        b3, g3, be3, m3, v3,
                                        scale1, shift1, scale2, shift2, scale3, shift3,
                                        bat, invcnt, out2d);

    // ---- fused: GEMM1 (unscaled) || bin histogram (LDS only) ----
    k_fused1<<<GEMM_BLOCKS + NBLK_BIN, 256, 0, stream>>>(x, Wt1, hs, dstp, L);

    // ---- CSR build: parallel scans, bin-scatter, per-bin CSR (+rs, dinv) ----
    k_scanA<<<NBIN, 512, 0, stream>>>(L, binTot);
    k_scanB<<<1, 512, 0, stream>>>(binTot, bin_ebase, rs);
    k_binscatter<<<NBLK_BIN, 256, 0, stream>>>(srcp, dstp, L, bin_ebase, bpack);
    k_bincsr<<<NBIN, 256, 0, stream>>>(bpack, bin_ebase, rs, dinv, csr);

    // ---- layer 1 gather (dinv[s],dinv[d]) + BN1 + ReLU + GEMM W2 -> xbuf (= scaled hs2) ----
    k_gath_gemm<true><<<GEMM_BLOCKS, 256, 0, stream>>>(
        hs, rs, csr, dinv, scale1, shift1, Wt2, xbuf);
    // ---- layer 2 gather (pre-scaled) + BN2 + ReLU + GEMM W3 -> hs (= scaled hs3) ----
    k_gath_gemm<false><<<GEMM_BLOCKS, 256, 0, stream>>>(
        xbuf, rs, csr, dinv, scale2, shift2, Wt3, hs);
    // ---- layer 3 gather + BN3 + ReLU + pool + final linear ----
    k_gather_pool<<<GATH_BLOCKS, 256, 0, stream>>>(
        hs, rs, csr, dinv, scale3, shift3, bat, invcnt, Wl, out2d);

    // ---- finalize ----
    k_final<<<2, 256, 0, stream>>>(out2d, bl, out);
}

// Round 8
// 478.972 us; speedup vs baseline: 1.1221x; 1.1221x over previous
//
#include <hip/hip_runtime.h>
#include <hip/hip_bf16.h>

// Problem constants (match reference)
#define NN 100000     // nodes
#define NE 1600000    // edges
#define HD 128        // feature/hidden dim
#define NG 512        // graphs
#define BN_EPS 1e-5f

#define GEMM_BLOCKS 1563          // ceil(NN/64)
#define NODES_PER_BLK 32          // gather: nodes per block (work-stealing queue; R7 A/B: 16->32)
#define GATH_BLOCKS (NN / NODES_PER_BLK)   // 3125, exact

// ---- bin-sort CSR build params ----
#define BIN_SHIFT 8
#define NBIN 391                  // ceil(NN/256)
#define TILE 4096                 // edges per binning block
#define NBLK_BIN 391              // ceil(NE/TILE)

typedef __attribute__((ext_vector_type(8))) short short8;
typedef __attribute__((ext_vector_type(4))) float floatx4;

// ---- bf16 helpers (RNE) ----
__device__ __forceinline__ ushort f2bf(float f) {
    union { float f; uint u; } v; v.f = f;
    uint r = (v.u + 0x7FFF + ((v.u >> 16) & 1)) >> 16;
    return (ushort)r;
}
__device__ __forceinline__ float bflo(uint u) { union { uint u; float f; } v; v.u = u << 16; return v.f; }
__device__ __forceinline__ float bfhi(uint u) { union { uint u; float f; } v; v.u = u & 0xFFFF0000u; return v.f; }

// ---------------- fused prep: W transpose (blk<192) | BN affine (192-194) | graph counts (195-196) ----------------
__global__ void k_prep_all(const float* __restrict__ W1, const float* __restrict__ W2,
                           const float* __restrict__ W3,
                           ushort* __restrict__ Wt1, ushort* __restrict__ Wt2,
                           ushort* __restrict__ Wt3,
                           const float* __restrict__ b1, const float* __restrict__ g1,
                           const float* __restrict__ be1, const float* __restrict__ m1,
                           const float* __restrict__ v1,
                           const float* __restrict__ b2, const float* __restrict__ g2,
                           const float* __restrict__ be2, const float* __restrict__ m2,
                           const float* __restrict__ v2,
                           const float* __restrict__ b3, const float* __restrict__ g3,
                           const float* __restrict__ be3, const float* __restrict__ m3,
                           const float* __restrict__ v3,
                           float* scale1, float* shift1, float* scale2, float* shift2,
                           float* scale3, float* shift3,
                           const int* __restrict__ bat, float* __restrict__ invcnt,
                           float* __restrict__ out2d) {
    int blk = blockIdx.x, tid = threadIdx.x;
    if (blk < 192) {
        int w = blk >> 6;
        int i = (blk & 63) * 256 + tid;
        const float* W = (w == 0) ? W1 : (w == 1) ? W2 : W3;
        ushort* Wt = (w == 0) ? Wt1 : (w == 1) ? Wt2 : Wt3;
        int k = i >> 7, n = i & 127;
        Wt[n * 128 + k] = f2bf(W[i]);
    } else if (blk < 195) {
        if (tid < 128) {
            int l = blk - 192;
            const float *b, *g, *be, *m, *v;
            float *sc, *sh;
            if (l == 0)      { b = b1; g = g1; be = be1; m = m1; v = v1; sc = scale1; sh = shift1; }
            else if (l == 1) { b = b2; g = g2; be = be2; m = m2; v = v2; sc = scale2; sh = shift2; }
            else             { b = b3; g = g3; be = be3; m = m3; v = v3; sc = scale3; sh = shift3; }
            float s = g[tid] * rsqrtf(v[tid] + BN_EPS);
            sc[tid] = s;
            sh[tid] = (b[tid] - m[tid]) * s + be[tid];
        }
    } else {
        int g = (blk - 195) * 256 + tid;
        if (g < NG) {
            int lo = 0, hi = NN;
            while (lo < hi) { int mid = (lo + hi) >> 1; if (bat[mid] < g) lo = mid + 1; else hi = mid; }
            int lo2 = lo, hi2 = NN;
            while (lo2 < hi2) { int mid = (lo2 + hi2) >> 1; if (bat[mid] < g + 1) lo2 = mid + 1; else hi2 = mid; }
            int cnt = lo2 - lo;
            invcnt[g] = 1.f / fmaxf((float)cnt, 1.f);
#pragma unroll
            for (int i = 0; i < 8; ++i) out2d[g * 8 + i] = 0.f;
        }
    }
}

// ---------------- fused: GEMM1 (fp32 x @ Wt1 -> unscaled bf16 hs)  ||  bin histogram (LDS, no global atomics) ----------------
__launch_bounds__(256)
__global__ void k_fused1(const float* __restrict__ x, const ushort* __restrict__ Wt,
                         ushort* __restrict__ hs,
                         const int* __restrict__ dst, int* __restrict__ L) {
    __shared__ int lh[NBIN];
    const int tid = threadIdx.x;
    if (blockIdx.x >= GEMM_BLOCKS) {
        // ---- bin histogram role: 391 blocks, 4096 edges each ----
        int blk = blockIdx.x - GEMM_BLOCKS;
        for (int i = tid; i < NBIN; i += 256) lh[i] = 0;
        __syncthreads();
        long base = (long)blk * TILE;
#pragma unroll 4
        for (int i = 0; i < TILE / 256; ++i) {
            long e = base + i * 256 + tid;
            if (e < NE) atomicAdd(&lh[dst[e] >> BIN_SHIFT], 1);
        }
        __syncthreads();
        for (int i = tid; i < NBIN; i += 256) L[i * NBLK_BIN + blk] = lh[i];
        return;
    }
    // ---- GEMM role: 4 waves, 64 rows, B-frags straight from global (L1-resident 32 KB) ----
    const int wave = tid >> 6, lane = tid & 63;
    const int m = lane & 15, kg = lane >> 4;
    const long row0 = (long)blockIdx.x * 64 + wave * 16;

    long arow = row0 + m;
    long arc = arow < NN ? arow : (NN - 1);
    const float* xf = x + arc * 128;
    short8 a[4];
#pragma unroll
    for (int s = 0; s < 4; ++s) {
        float4 f0 = *(const float4*)(xf + s * 32 + kg * 8);
        float4 f1 = *(const float4*)(xf + s * 32 + kg * 8 + 4);
        short8 t;
        t[0] = (short)f2bf(f0.x); t[1] = (short)f2bf(f0.y);
        t[2] = (short)f2bf(f0.z); t[3] = (short)f2bf(f0.w);
        t[4] = (short)f2bf(f1.x); t[5] = (short)f2bf(f1.y);
        t[6] = (short)f2bf(f1.z); t[7] = (short)f2bf(f1.w);
        a[s] = t;
    }

    floatx4 acc[8];
#pragma unroll
    for (int ct = 0; ct < 8; ++ct) acc[ct] = (floatx4){0.f, 0.f, 0.f, 0.f};

#pragma unroll
    for (int s = 0; s < 4; ++s) {
#pragma unroll
        for (int ct = 0; ct < 8; ++ct) {
            short8 b = *(const short8*)(Wt + (ct * 16 + m) * 128 + s * 32 + kg * 8);
            acc[ct] = __builtin_amdgcn_mfma_f32_16x16x32_bf16(a[s], b, acc[ct], 0, 0, 0);
        }
    }

#pragma unroll
    for (int r = 0; r < 4; ++r) {
        long orow = row0 + kg * 4 + r;
        if (orow < NN) {
#pragma unroll
            for (int ct = 0; ct < 8; ++ct)
                hs[orow * 128 + ct * 16 + m] = f2bf(acc[ct][r]);   // unscaled
        }
    }
}

// ---------------- scanA: per-bin exclusive scan across blocks (one block per bin) ----------------
__global__ void k_scanA(int* __restrict__ L, int* __restrict__ binTot) {
    __shared__ int s[512];
    int b = blockIdx.x, t = threadIdx.x;   // 512 threads
    int v = (t < NBLK_BIN) ? L[b * NBLK_BIN + t] : 0;
    s[t] = v;
    __syncthreads();
    for (int o = 1; o < 512; o <<= 1) {
        int x = (t >= o) ? s[t - o] : 0;
        __syncthreads();
        s[t] += x;
        __syncthreads();
    }
    if (t < NBLK_BIN) L[b * NBLK_BIN + t] = s[t] - v;   // exclusive within bin
    if (t == 511) binTot[b] = s[511];
}

// ---------------- scanB: exclusive scan over bin totals -> bin edge bases ----------------
__global__ void k_scanB(const int* __restrict__ binTot, int* __restrict__ bin_ebase,
                        int* __restrict__ rs) {
    __shared__ int s[512];
    int t = threadIdx.x;
    int v = (t < NBIN) ? binTot[t] : 0;
    s[t] = v;
    __syncthreads();
    for (int o = 1; o < 512; o <<= 1) {
        int x = (t >= o) ? s[t - o] : 0;
        __syncthreads();
        s[t] += x;
        __syncthreads();
    }
    if (t < NBIN) bin_ebase[t] = s[t] - v;
    if (t == 0) { bin_ebase[NBIN] = NE; rs[NN] = NE; }
}

// ---------------- C: scatter edges into bin-grouped order (LDS cursors only) ----------------
__launch_bounds__(256)
__global__ void k_binscatter(const int* __restrict__ src, const int* __restrict__ dst,
                             const int* __restrict__ L, const int* __restrict__ bin_ebase,
                             uint* __restrict__ bpack) {
    __shared__ int off[NBIN];
    int t = threadIdx.x, blk = blockIdx.x;
    for (int i = t; i < NBIN; i += 256) off[i] = L[i * NBLK_BIN + blk] + bin_ebase[i];
    __syncthreads();
    long base = (long)blk * TILE;
#pragma unroll 4
    for (int i = 0; i < TILE / 256; ++i) {
        long e = base + i * 256 + t;
        if (e < NE) {
            int d = dst[e];
            int p = atomicAdd(&off[d >> BIN_SHIFT], 1);
            bpack[p] = (uint)src[e] | ((uint)(d & 255) << 24);   // src<2^17, local node in top 8
        }
    }
}

// ---------------- D: per-bin exact CSR + rs + dinv (all LDS) ----------------
__launch_bounds__(256)
__global__ void k_bincsr(const uint* __restrict__ bpack, const int* __restrict__ bin_ebase,
                         int* __restrict__ rs, float* __restrict__ dinv,
                         int* __restrict__ csr) {
    __shared__ int cnt[256];
    __shared__ int sc[256];
    __shared__ int run[256];
    int t = threadIdx.x, b = blockIdx.x;
    int e0 = bin_ebase[b], e1 = bin_ebase[b + 1];
    cnt[t] = 0;
    __syncthreads();
    for (int e = e0 + t; e < e1; e += 256) atomicAdd(&cnt[bpack[e] >> 24], 1);
    __syncthreads();
    int c = cnt[t];
    sc[t] = c;
    __syncthreads();
    for (int o = 1; o < 256; o <<= 1) {
        int x = (t >= o) ? sc[t - o] : 0;
        __syncthreads();
        sc[t] += x;
        __syncthreads();
    }
    int excl = sc[t] - c;
    int node = (b << BIN_SHIFT) + t;
    if (node < NN) {
        rs[node] = e0 + excl;
        dinv[node] = rsqrtf((float)(c + 1));   // +1 self-loop
    }
    run[t] = e0 + excl;
    __syncthreads();
    for (int e = e0 + t; e < e1; e += 256) {
        uint u = bpack[e];
        int p = atomicAdd(&run[u >> 24], 1);
        csr[p] = (int)(u & 0xFFFFFFu);
    }
}

// ---------------- MFMA GEMM layers 2/3 (LDS-staged W, scaled epilogue) ----------------
#define WT_STRIDE 136
__launch_bounds__(256)
__global__ void k_gemm_l23(const ushort* __restrict__ xb, const ushort* __restrict__ Wt,
                           const float* __restrict__ dinv, ushort* __restrict__ hs) {
    __shared__ ushort sWt[128 * WT_STRIDE];
    const int tid = threadIdx.x;
    for (int i = tid; i < 2048; i += 256) {
        int row = i >> 4, seg = i & 15;
        *(uint4*)&sWt[row * WT_STRIDE + seg * 8] = *(const uint4*)(Wt + row * 128 + seg * 8);
    }
    __syncthreads();

    const int wave = tid >> 6, lane = tid & 63;
    const int m = lane & 15, kg = lane >> 4;
    const long row0 = (long)blockIdx.x * 64 + wave * 16;

    long arow = row0 + m;
    long arc = arow < NN ? arow : (NN - 1);
    short8 a[4];
#pragma unroll
    for (int s = 0; s < 4; ++s)
        a[s] = *(const short8*)(xb + arc * 128 + s * 32 + kg * 8);

    floatx4 acc[8];
#pragma unroll
    for (int ct = 0; ct < 8; ++ct) acc[ct] = (floatx4){0.f, 0.f, 0.f, 0.f};

#pragma unroll
    for (int s = 0; s < 4; ++s) {
#pragma unroll
        for (int ct = 0; ct < 8; ++ct) {
            short8 b = *(const short8*)&sWt[(ct * 16 + m) * WT_STRIDE + s * 32 + kg * 8];
            acc[ct] = __builtin_amdgcn_mfma_f32_16x16x32_bf16(a[s], b, acc[ct], 0, 0, 0);
        }
    }

#pragma unroll
    for (int r = 0; r < 4; ++r) {
        long orow = row0 + kg * 4 + r;
        if (orow < NN) {
            float dd = dinv[orow];
#pragma unroll
            for (int ct = 0; ct < 8; ++ct)
                hs[orow * 128 + ct * 16 + m] = f2bf(acc[ct][r] * dd);
        }
    }
}

// ---------------- gather + BN + ReLU fused: WORK-STEALING WAVES ----------------
// Block owns NODES_PER_BLK=32 consecutive nodes; its 4 waves pull node indices
// from an LDS counter (dynamic intra-block balance; blocks stay short-lived,
// writes stay coalesced). 32-node queue halves the block-end tail fraction vs 16.
// Steal loop is explicitly bounded (nextn monotone, <= NODES_PER_BLK+1 pulls).
// lane = (sub, c): sub = lane>>4 is one of 4 parallel edge slots, c = lane&15
// is the 8-feature column segment; 4-row quads per slot, indices prefetched.
// POOL=true (layer 3): dot with Wl in-register, one fp32 atomic per node.
template <bool SCALE_SRC, bool POOL>
__launch_bounds__(256)
__global__ void k_gather_w(const ushort* __restrict__ hs, const int* __restrict__ rs,
                           const int* __restrict__ csr, const float* __restrict__ dinv,
                           const float* __restrict__ scale, const float* __restrict__ shift,
                           ushort* __restrict__ xout,
                           const int* __restrict__ bat, const float* __restrict__ invcnt,
                           const float* __restrict__ Wl, float* __restrict__ out2d) {
    __shared__ int nextn;
    const int tid = threadIdx.x;
    if (tid == 0) nextn = 0;
    __syncthreads();
    const int lane = tid & 63;
    const int sub = lane >> 4;
    const int c0 = (lane & 15) * 8;
    const int base = blockIdx.x * NODES_PER_BLK;

    for (int it = 0; it <= NODES_PER_BLK; ++it) {
        int myn = 0;
        if (lane == 0) myn = atomicAdd(&nextn, 1);
        myn = __shfl(myn, 0);
        if (myn >= NODES_PER_BLK) break;
        const int d = base + myn;

        const int e0 = rs[d], e1 = rs[d + 1];
        const float dd = dinv[d];

        float a0 = 0.f, a1 = 0.f, a2 = 0.f, a3 = 0.f,
              a4 = 0.f, a5 = 0.f, a6 = 0.f, a7 = 0.f;

        if (sub == 0) {   // self-loop term
            uint4 sv = *(const uint4*)(hs + (long)d * 128 + c0);
            float w = SCALE_SRC ? dd : 1.0f;
            a0 = w * bflo(sv.x); a1 = w * bfhi(sv.x);
            a2 = w * bflo(sv.y); a3 = w * bfhi(sv.y);
            a4 = w * bflo(sv.z); a5 = w * bfhi(sv.z);
            a6 = w * bflo(sv.w); a7 = w * bfhi(sv.w);
        }

        int j = e0 + sub;
        // ---- quad loop: rows j, j+4, j+8, j+12; next quad's indices prefetched ----
        int s0 = 0, s1 = 0, s2 = 0, s3 = 0;
        bool have = (j + 12 < e1);
        if (have) { s0 = csr[j]; s1 = csr[j + 4]; s2 = csr[j + 8]; s3 = csr[j + 12]; }
        while (have) {
            int jn = j + 16;
            bool nxt = (jn + 12 < e1);
            int n0 = 0, n1 = 0, n2 = 0, n3 = 0;
            if (nxt) { n0 = csr[jn]; n1 = csr[jn + 4]; n2 = csr[jn + 8]; n3 = csr[jn + 12]; }
            float w0 = 1.f, w1 = 1.f, w2 = 1.f, w3 = 1.f;
            if (SCALE_SRC) { w0 = dinv[s0]; w1 = dinv[s1]; w2 = dinv[s2]; w3 = dinv[s3]; }
            uint4 v0 = *(const uint4*)(hs + (long)s0 * 128 + c0);
            uint4 v1 = *(const uint4*)(hs + (long)s1 * 128 + c0);
            uint4 v2 = *(const uint4*)(hs + (long)s2 * 128 + c0);
            uint4 v3 = *(const uint4*)(hs + (long)s3 * 128 + c0);
            a0 += w0 * bflo(v0.x) + w1 * bflo(v1.x) + w2 * bflo(v2.x) + w3 * bflo(v3.x);
            a1 += w0 * bfhi(v0.x) + w1 * bfhi(v1.x) + w2 * bfhi(v2.x) + w3 * bfhi(v3.x);
            a2 += w0 * bflo(v0.y) + w1 * bflo(v1.y) + w2 * bflo(v2.y) + w3 * bflo(v3.y);
            a3 += w0 * bfhi(v0.y) + w1 * bfhi(v1.y) + w2 * bfhi(v2.y) + w3 * bfhi(v3.y);
            a4 += w0 * bflo(v0.z) + w1 * bflo(v1.z) + w2 * bflo(v2.z) + w3 * bflo(v3.z);
            a5 += w0 * bfhi(v0.z) + w1 * bfhi(v1.z) + w2 * bfhi(v2.z) + w3 * bfhi(v3.z);
            a6 += w0 * bflo(v0.w) + w1 * bflo(v1.w) + w2 * bflo(v2.w) + w3 * bflo(v3.w);
            a7 += w0 * bfhi(v0.w) + w1 * bfhi(v1.w) + w2 * bfhi(v2.w) + w3 * bfhi(v3.w);
            j = jn; s0 = n0; s1 = n1; s2 = n2; s3 = n3; have = nxt;
        }
        // ---- tail: up to 3 rows (j, j+4, j+8), all loads issued together ----
        if (j < e1) {
            bool b1 = (j + 4) < e1, b2 = (j + 8) < e1;
            int t0 = csr[j];
            int t1 = b1 ? csr[j + 4] : t0;
            int t2 = b2 ? csr[j + 8] : t0;
            float w0 = SCALE_SRC ? dinv[t0] : 1.f;
            float w1 = b1 ? (SCALE_SRC ? dinv[t1] : 1.f) : 0.f;
            float w2 = b2 ? (SCALE_SRC ? dinv[t2] : 1.f) : 0.f;
            uint4 v0 = *(const uint4*)(hs + (long)t0 * 128 + c0);
            uint4 v1 = *(const uint4*)(hs + (long)t1 * 128 + c0);
            uint4 v2 = *(const uint4*)(hs + (long)t2 * 128 + c0);
            a0 += w0 * bflo(v0.x) + w1 * bflo(v1.x) + w2 * bflo(v2.x);
            a1 += w0 * bfhi(v0.x) + w1 * bfhi(v1.x) + w2 * bfhi(v2.x);
            a2 += w0 * bflo(v0.y) + w1 * bflo(v1.y) + w2 * bflo(v2.y);
            a3 += w0 * bfhi(v0.y) + w1 * bfhi(v1.y) + w2 * bfhi(v2.y);
            a4 += w0 * bflo(v0.z) + w1 * bflo(v1.z) + w2 * bflo(v2.z);
            a5 += w0 * bfhi(v0.z) + w1 * bfhi(v1.z) + w2 * bfhi(v2.z);
            a6 += w0 * bflo(v0.w) + w1 * bflo(v1.w) + w2 * bflo(v2.w);
            a7 += w0 * bfhi(v0.w) + w1 * bfhi(v1.w) + w2 * bfhi(v2.w);
        }

        // reduce across the 4 edge slots (lanes differing in bits 4,5)
        a0 += __shfl_xor(a0, 16); a1 += __shfl_xor(a1, 16);
        a2 += __shfl_xor(a2, 16); a3 += __shfl_xor(a3, 16);
        a4 += __shfl_xor(a4, 16); a5 += __shfl_xor(a5, 16);
        a6 += __shfl_xor(a6, 16); a7 += __shfl_xor(a7, 16);
        a0 += __shfl_xor(a0, 32); a1 += __shfl_xor(a1, 32);
        a2 += __shfl_xor(a2, 32); a3 += __shfl_xor(a3, 32);
        a4 += __shfl_xor(a4, 32); a5 += __shfl_xor(a5, 32);
        a6 += __shfl_xor(a6, 32); a7 += __shfl_xor(a7, 32);

        float pd = 0.f;
        if (sub == 0) {
            float4 sca = *(const float4*)(scale + c0);
            float4 scb = *(const float4*)(scale + c0 + 4);
            float4 sha = *(const float4*)(shift + c0);
            float4 shb = *(const float4*)(shift + c0 + 4);
            float r0 = fmaxf(dd * a0 * sca.x + sha.x, 0.f);
            float r1 = fmaxf(dd * a1 * sca.y + sha.y, 0.f);
            float r2 = fmaxf(dd * a2 * sca.z + sha.z, 0.f);
            float r3 = fmaxf(dd * a3 * sca.w + sha.w, 0.f);
            float r4 = fmaxf(dd * a4 * scb.x + shb.x, 0.f);
            float r5 = fmaxf(dd * a5 * scb.y + shb.y, 0.f);
            float r6 = fmaxf(dd * a6 * scb.z + shb.z, 0.f);
            float r7 = fmaxf(dd * a7 * scb.w + shb.w, 0.f);
            if constexpr (POOL) {
                float4 wa = *(const float4*)(Wl + c0);
                float4 wb = *(const float4*)(Wl + c0 + 4);
                pd = r0 * wa.x + r1 * wa.y + r2 * wa.z + r3 * wa.w +
                     r4 * wb.x + r5 * wb.y + r6 * wb.z + r7 * wb.w;
            } else {
                uint4 o;
                o.x = (uint)f2bf(r0) | ((uint)f2bf(r1) << 16);
                o.y = (uint)f2bf(r2) | ((uint)f2bf(r3) << 16);
                o.z = (uint)f2bf(r4) | ((uint)f2bf(r5) << 16);
                o.w = (uint)f2bf(r6) | ((uint)f2bf(r7) << 16);
                *(uint4*)(xout + (long)d * 128 + c0) = o;
            }
        }
        if constexpr (POOL) {
            pd += __shfl_xor(pd, 1);
            pd += __shfl_xor(pd, 2);
            pd += __shfl_xor(pd, 4);
            pd += __shfl_xor(pd, 8);
            if (lane == 0) {
                int g = bat[d];
                atomicAdd(&out2d[g * 8 + (d & 7)], pd * invcnt[g]);
            }
        }
    }
}

// ---------------- finalize: out[g] = bl + sum of 8 slots ----------------
__global__ void k_final(const float* __restrict__ out2d, const float* __restrict__ bl,
                        float* __restrict__ out) {
    int g = blockIdx.x * 256 + threadIdx.x;
    if (g >= NG) return;
    float s = bl[0];
#pragma unroll
    for (int i = 0; i < 8; ++i) s += out2d[g * 8 + i];
    out[g] = s;
}

// ---------------- launch ----------------
extern "C" void kernel_launch(void* const* d_in, const int* in_sizes, int n_in,
                              void* d_out, int out_size, void* d_ws, size_t ws_size,
                              hipStream_t stream) {
    const float* x   = (const float*)d_in[0];
    const int*   ei  = (const int*)d_in[1];
    const int*   bat = (const int*)d_in[2];
    const float* W1  = (const float*)d_in[3];
    const float* b1  = (const float*)d_in[4];
    const float* g1  = (const float*)d_in[5];
    const float* be1 = (const float*)d_in[6];
    const float* m1  = (const float*)d_in[7];
    const float* v1  = (const float*)d_in[8];
    const float* W2  = (const float*)d_in[9];
    const float* b2  = (const float*)d_in[10];
    const float* g2  = (const float*)d_in[11];
    const float* be2 = (const float*)d_in[12];
    const float* m2  = (const float*)d_in[13];
    const float* v2  = (const float*)d_in[14];
    const float* W3  = (const float*)d_in[15];
    const float* b3  = (const float*)d_in[16];
    const float* g3  = (const float*)d_in[17];
    const float* be3 = (const float*)d_in[18];
    const float* m3  = (const float*)d_in[19];
    const float* v3  = (const float*)d_in[20];
    const float* Wl  = (const float*)d_in[21];
    const float* bl  = (const float*)d_in[22];
    float* out = (float*)d_out;

    const int* srcp = ei;        // edge_index[0]
    const int* dstp = ei + NE;   // edge_index[1]

    // ---- workspace layout ----
    char* ws = (char*)d_ws;
    size_t off = 0;
    auto alloc = [&](size_t bytes) { char* p = ws + off; off += (bytes + 255) & ~255ULL; return p; };
    float*  dinv     = (float*) alloc(NN * 4);
    int*    rs       = (int*)   alloc((NN + 1) * 4);
    int*    L        = (int*)   alloc((size_t)NBIN * NBLK_BIN * 4);   // block-bin table, 612 KB
    int*    binTot   = (int*)   alloc((NBIN + 1) * 4);
    int*    bin_ebase= (int*)   alloc((NBIN + 1) * 4);
    uint*   bpack    = (uint*)  alloc((size_t)NE * 4);   // 6.4 MB (bin-grouped edges)
    int*    csr      = (int*)   alloc((size_t)NE * 4);   // 6.4 MB
    float*  scale1 = (float*) alloc(HD * 4);
    float*  shift1 = (float*) alloc(HD * 4);
    float*  scale2 = (float*) alloc(HD * 4);
    float*  shift2 = (float*) alloc(HD * 4);
    float*  scale3 = (float*) alloc(HD * 4);
    float*  shift3 = (float*) alloc(HD * 4);
    float*  invcnt = (float*) alloc(NG * 4);
    float*  out2d  = (float*) alloc(NG * 8 * 4);
    ushort* Wt1    = (ushort*)alloc(128 * 128 * 2);    // 32 KB
    ushort* Wt2    = (ushort*)alloc(128 * 128 * 2);
    ushort* Wt3    = (ushort*)alloc(128 * 128 * 2);
    ushort* hs     = (ushort*)alloc((size_t)NN * HD * 2);   // 25.6 MB
    ushort* xbuf   = (ushort*)alloc((size_t)NN * HD * 2);   // 25.6 MB

    // ---- prep: W transpose + BN affine + graph inv-counts (one launch) ----
    k_prep_all<<<197, 256, 0, stream>>>(W1, W2, W3, Wt1, Wt2, Wt3,
                                        b1, g1, be1, m1, v1, b2, g2, be2, m2, v2,
                                        b3, g3, be3, m3, v3,
                                        scale1, shift1, scale2, shift2, scale3, shift3,
                                        bat, invcnt, out2d);

    // ---- fused: GEMM1 (unscaled) || bin histogram (LDS only) ----
    k_fused1<<<GEMM_BLOCKS + NBLK_BIN, 256, 0, stream>>>(x, Wt1, hs, dstp, L);

    // ---- CSR build: parallel scans, bin-scatter, per-bin CSR (+rs, dinv) ----
    k_scanA<<<NBIN, 512, 0, stream>>>(L, binTot);
    k_scanB<<<1, 512, 0, stream>>>(binTot, bin_ebase, rs);
    k_binscatter<<<NBLK_BIN, 256, 0, stream>>>(srcp, dstp, L, bin_ebase, bpack);
    k_bincsr<<<NBIN, 256, 0, stream>>>(bpack, bin_ebase, rs, dinv, csr);

    // ---- layer 1 gather (applies dinv[s] and dinv[d]) ----
    k_gather_w<true, false><<<GATH_BLOCKS, 256, 0, stream>>>(
        hs, rs, csr, dinv, scale1, shift1, xbuf, nullptr, nullptr, nullptr, nullptr);
    // ---- layer 2 ----
    k_gemm_l23<<<GEMM_BLOCKS, 256, 0, stream>>>(xbuf, Wt2, dinv, hs);
    k_gather_w<false, false><<<GATH_BLOCKS, 256, 0, stream>>>(
        hs, rs, csr, dinv, scale2, shift2, xbuf, nullptr, nullptr, nullptr, nullptr);
    // ---- layer 3 ----
    k_gemm_l23<<<GEMM_BLOCKS, 256, 0, stream>>>(xbuf, Wt3, dinv, hs);
    k_gather_w<false, true><<<GATH_BLOCKS, 256, 0, stream>>>(
        hs, rs, csr, dinv, scale3, shift3, nullptr, bat, invcnt, Wl, out2d);

    // ---- finalize ----
    k_final<<<2, 256, 0, stream>>>(out2d, bl, out);
}

// Round 9
// 454.409 us; speedup vs baseline: 1.1828x; 1.0541x over previous
//
#include <hip/hip_runtime.h>
#include <hip/hip_bf16.h>

// Problem constants (match reference)
#define NN 100000     // nodes
#define NE 1600000    // edges
#define HD 128        // feature/hidden dim
#define NG 512        // graphs
#define BN_EPS 1e-5f

#define GEMM_BLOCKS 1563          // ceil(NN/64)
#define NODES_PER_BLK 8           // gather: nodes per 2-wave block (work-stealing queue)
#define GATH_BLOCKS (NN / NODES_PER_BLK)   // 12500, exact

// ---- bin-sort CSR build params ----
#define BIN_SHIFT 8
#define NBIN 391                  // ceil(NN/256)
#define TILE 4096                 // edges per binning block
#define NBLK_BIN 391              // ceil(NE/TILE)

typedef __attribute__((ext_vector_type(8))) short short8;
typedef __attribute__((ext_vector_type(4))) float floatx4;

// ---- bf16 helpers (RNE) ----
__device__ __forceinline__ ushort f2bf(float f) {
    union { float f; uint u; } v; v.f = f;
    uint r = (v.u + 0x7FFF + ((v.u >> 16) & 1)) >> 16;
    return (ushort)r;
}
__device__ __forceinline__ float bflo(uint u) { union { uint u; float f; } v; v.u = u << 16; return v.f; }
__device__ __forceinline__ float bfhi(uint u) { union { uint u; float f; } v; v.u = u & 0xFFFF0000u; return v.f; }

// ---------------- fused prep: W transpose (blk<192) | BN affine (192-194) | graph counts (195-196) ----------------
__global__ void k_prep_all(const float* __restrict__ W1, const float* __restrict__ W2,
                           const float* __restrict__ W3,
                           ushort* __restrict__ Wt1, ushort* __restrict__ Wt2,
                           ushort* __restrict__ Wt3,
                           const float* __restrict__ b1, const float* __restrict__ g1,
                           const float* __restrict__ be1, const float* __restrict__ m1,
                           const float* __restrict__ v1,
                           const float* __restrict__ b2, const float* __restrict__ g2,
                           const float* __restrict__ be2, const float* __restrict__ m2,
                           const float* __restrict__ v2,
                           const float* __restrict__ b3, const float* __restrict__ g3,
                           const float* __restrict__ be3, const float* __restrict__ m3,
                           const float* __restrict__ v3,
                           float* scale1, float* shift1, float* scale2, float* shift2,
                           float* scale3, float* shift3,
                           const int* __restrict__ bat, float* __restrict__ invcnt,
                           float* __restrict__ out2d) {
    int blk = blockIdx.x, tid = threadIdx.x;
    if (blk < 192) {
        int w = blk >> 6;
        int i = (blk & 63) * 256 + tid;
        const float* W = (w == 0) ? W1 : (w == 1) ? W2 : W3;
        ushort* Wt = (w == 0) ? Wt1 : (w == 1) ? Wt2 : Wt3;
        int k = i >> 7, n = i & 127;
        Wt[n * 128 + k] = f2bf(W[i]);
    } else if (blk < 195) {
        if (tid < 128) {
            int l = blk - 192;
            const float *b, *g, *be, *m, *v;
            float *sc, *sh;
            if (l == 0)      { b = b1; g = g1; be = be1; m = m1; v = v1; sc = scale1; sh = shift1; }
            else if (l == 1) { b = b2; g = g2; be = be2; m = m2; v = v2; sc = scale2; sh = shift2; }
            else             { b = b3; g = g3; be = be3; m = m3; v = v3; sc = scale3; sh = shift3; }
            float s = g[tid] * rsqrtf(v[tid] + BN_EPS);
            sc[tid] = s;
            sh[tid] = (b[tid] - m[tid]) * s + be[tid];
        }
    } else {
        int g = (blk - 195) * 256 + tid;
        if (g < NG) {
            int lo = 0, hi = NN;
            while (lo < hi) { int mid = (lo + hi) >> 1; if (bat[mid] < g) lo = mid + 1; else hi = mid; }
            int lo2 = lo, hi2 = NN;
            while (lo2 < hi2) { int mid = (lo2 + hi2) >> 1; if (bat[mid] < g + 1) lo2 = mid + 1; else hi2 = mid; }
            int cnt = lo2 - lo;
            invcnt[g] = 1.f / fmaxf((float)cnt, 1.f);
#pragma unroll
            for (int i = 0; i < 8; ++i) out2d[g * 8 + i] = 0.f;
        }
    }
}

// ---------------- fused: GEMM1 (fp32 x @ Wt1 -> unscaled bf16 hs)  ||  bin histogram (LDS, no global atomics) ----------------
__launch_bounds__(256)
__global__ void k_fused1(const float* __restrict__ x, const ushort* __restrict__ Wt,
                         ushort* __restrict__ hs,
                         const int* __restrict__ dst, int* __restrict__ L) {
    __shared__ int lh[NBIN];
    const int tid = threadIdx.x;
    if (blockIdx.x >= GEMM_BLOCKS) {
        // ---- bin histogram role: 391 blocks, 4096 edges each ----
        int blk = blockIdx.x - GEMM_BLOCKS;
        for (int i = tid; i < NBIN; i += 256) lh[i] = 0;
        __syncthreads();
        long base = (long)blk * TILE;
#pragma unroll 4
        for (int i = 0; i < TILE / 256; ++i) {
            long e = base + i * 256 + tid;
            if (e < NE) atomicAdd(&lh[dst[e] >> BIN_SHIFT], 1);
        }
        __syncthreads();
        for (int i = tid; i < NBIN; i += 256) L[i * NBLK_BIN + blk] = lh[i];
        return;
    }
    // ---- GEMM role: 4 waves, 64 rows, B-frags straight from global (L1-resident 32 KB) ----
    const int wave = tid >> 6, lane = tid & 63;
    const int m = lane & 15, kg = lane >> 4;
    const long row0 = (long)blockIdx.x * 64 + wave * 16;

    long arow = row0 + m;
    long arc = arow < NN ? arow : (NN - 1);
    const float* xf = x + arc * 128;
    short8 a[4];
#pragma unroll
    for (int s = 0; s < 4; ++s) {
        float4 f0 = *(const float4*)(xf + s * 32 + kg * 8);
        float4 f1 = *(const float4*)(xf + s * 32 + kg * 8 + 4);
        short8 t;
        t[0] = (short)f2bf(f0.x); t[1] = (short)f2bf(f0.y);
        t[2] = (short)f2bf(f0.z); t[3] = (short)f2bf(f0.w);
        t[4] = (short)f2bf(f1.x); t[5] = (short)f2bf(f1.y);
        t[6] = (short)f2bf(f1.z); t[7] = (short)f2bf(f1.w);
        a[s] = t;
    }

    floatx4 acc[8];
#pragma unroll
    for (int ct = 0; ct < 8; ++ct) acc[ct] = (floatx4){0.f, 0.f, 0.f, 0.f};

#pragma unroll
    for (int s = 0; s < 4; ++s) {
#pragma unroll
        for (int ct = 0; ct < 8; ++ct) {
            short8 b = *(const short8*)(Wt + (ct * 16 + m) * 128 + s * 32 + kg * 8);
            acc[ct] = __builtin_amdgcn_mfma_f32_16x16x32_bf16(a[s], b, acc[ct], 0, 0, 0);
        }
    }

#pragma unroll
    for (int r = 0; r < 4; ++r) {
        long orow = row0 + kg * 4 + r;
        if (orow < NN) {
#pragma unroll
            for (int ct = 0; ct < 8; ++ct)
                hs[orow * 128 + ct * 16 + m] = f2bf(acc[ct][r]);   // unscaled
        }
    }
}

// ---------------- scanA: per-bin exclusive scan across blocks (one block per bin) ----------------
__global__ void k_scanA(int* __restrict__ L, int* __restrict__ binTot) {
    __shared__ int s[512];
    int b = blockIdx.x, t = threadIdx.x;   // 512 threads
    int v = (t < NBLK_BIN) ? L[b * NBLK_BIN + t] : 0;
    s[t] = v;
    __syncthreads();
    for (int o = 1; o < 512; o <<= 1) {
        int x = (t >= o) ? s[t - o] : 0;
        __syncthreads();
        s[t] += x;
        __syncthreads();
    }
    if (t < NBLK_BIN) L[b * NBLK_BIN + t] = s[t] - v;   // exclusive within bin
    if (t == 511) binTot[b] = s[511];
}

// ---------------- scanB: exclusive scan over bin totals -> bin edge bases ----------------
__global__ void k_scanB(const int* __restrict__ binTot, int* __restrict__ bin_ebase,
                        int* __restrict__ rs) {
    __shared__ int s[512];
    int t = threadIdx.x;
    int v = (t < NBIN) ? binTot[t] : 0;
    s[t] = v;
    __syncthreads();
    for (int o = 1; o < 512; o <<= 1) {
        int x = (t >= o) ? s[t - o] : 0;
        __syncthreads();
        s[t] += x;
        __syncthreads();
    }
    if (t < NBIN) bin_ebase[t] = s[t] - v;
    if (t == 0) { bin_ebase[NBIN] = NE; rs[NN] = NE; }
}

// ---------------- C: scatter edges into bin-grouped order (LDS cursors only) ----------------
__launch_bounds__(256)
__global__ void k_binscatter(const int* __restrict__ src, const int* __restrict__ dst,
                             const int* __restrict__ L, const int* __restrict__ bin_ebase,
                             uint* __restrict__ bpack) {
    __shared__ int off[NBIN];
    int t = threadIdx.x, blk = blockIdx.x;
    for (int i = t; i < NBIN; i += 256) off[i] = L[i * NBLK_BIN + blk] + bin_ebase[i];
    __syncthreads();
    long base = (long)blk * TILE;
#pragma unroll 4
    for (int i = 0; i < TILE / 256; ++i) {
        long e = base + i * 256 + t;
        if (e < NE) {
            int d = dst[e];
            int p = atomicAdd(&off[d >> BIN_SHIFT], 1);
            bpack[p] = (uint)src[e] | ((uint)(d & 255) << 24);   // src<2^17, local node in top 8
        }
    }
}

// ---------------- D: per-bin exact CSR + rs + dinv (all LDS) ----------------
__launch_bounds__(256)
__global__ void k_bincsr(const uint* __restrict__ bpack, const int* __restrict__ bin_ebase,
                         int* __restrict__ rs, float* __restrict__ dinv,
                         int* __restrict__ csr) {
    __shared__ int cnt[256];
    __shared__ int sc[256];
    __shared__ int run[256];
    int t = threadIdx.x, b = blockIdx.x;
    int e0 = bin_ebase[b], e1 = bin_ebase[b + 1];
    cnt[t] = 0;
    __syncthreads();
    for (int e = e0 + t; e < e1; e += 256) atomicAdd(&cnt[bpack[e] >> 24], 1);
    __syncthreads();
    int c = cnt[t];
    sc[t] = c;
    __syncthreads();
    for (int o = 1; o < 256; o <<= 1) {
        int x = (t >= o) ? sc[t - o] : 0;
        __syncthreads();
        sc[t] += x;
        __syncthreads();
    }
    int excl = sc[t] - c;
    int node = (b << BIN_SHIFT) + t;
    if (node < NN) {
        rs[node] = e0 + excl;
        dinv[node] = rsqrtf((float)(c + 1));   // +1 self-loop
    }
    run[t] = e0 + excl;
    __syncthreads();
    for (int e = e0 + t; e < e1; e += 256) {
        uint u = bpack[e];
        int p = atomicAdd(&run[u >> 24], 1);
        csr[p] = (int)(u & 0xFFFFFFu);
    }
}

// ---------------- MFMA GEMM layers 2/3 (LDS-staged W, scaled epilogue) ----------------
#define WT_STRIDE 136
__launch_bounds__(256)
__global__ void k_gemm_l23(const ushort* __restrict__ xb, const ushort* __restrict__ Wt,
                           const float* __restrict__ dinv, ushort* __restrict__ hs) {
    __shared__ ushort sWt[128 * WT_STRIDE];
    const int tid = threadIdx.x;
    for (int i = tid; i < 2048; i += 256) {
        int row = i >> 4, seg = i & 15;
        *(uint4*)&sWt[row * WT_STRIDE + seg * 8] = *(const uint4*)(Wt + row * 128 + seg * 8);
    }
    __syncthreads();

    const int wave = tid >> 6, lane = tid & 63;
    const int m = lane & 15, kg = lane >> 4;
    const long row0 = (long)blockIdx.x * 64 + wave * 16;

    long arow = row0 + m;
    long arc = arow < NN ? arow : (NN - 1);
    short8 a[4];
#pragma unroll
    for (int s = 0; s < 4; ++s)
        a[s] = *(const short8*)(xb + arc * 128 + s * 32 + kg * 8);

    floatx4 acc[8];
#pragma unroll
    for (int ct = 0; ct < 8; ++ct) acc[ct] = (floatx4){0.f, 0.f, 0.f, 0.f};

#pragma unroll
    for (int s = 0; s < 4; ++s) {
#pragma unroll
        for (int ct = 0; ct < 8; ++ct) {
            short8 b = *(const short8*)&sWt[(ct * 16 + m) * WT_STRIDE + s * 32 + kg * 8];
            acc[ct] = __builtin_amdgcn_mfma_f32_16x16x32_bf16(a[s], b, acc[ct], 0, 0, 0);
        }
    }

#pragma unroll
    for (int r = 0; r < 4; ++r) {
        long orow = row0 + kg * 4 + r;
        if (orow < NN) {
            float dd = dinv[orow];
#pragma unroll
            for (int ct = 0; ct < 8; ++ct)
                hs[orow * 128 + ct * 16 + m] = f2bf(acc[ct][r] * dd);
        }
    }
}

// ---------------- gather + BN + ReLU fused: WORK-STEALING WAVES, 2-wave blocks ----------------
// Block = 128 threads (2 waves) owning NODES_PER_BLK=8 consecutive nodes via an
// LDS counter. Same 4 nodes/wave average as the proven 4-wave/16-node config,
// but block-retire granularity halves: a straggler node strands at most ONE
// sibling wave, and the dispatcher backfills with whole fresh blocks.
// Steal loop is explicitly bounded (nextn monotone, <= NODES_PER_BLK+1 pulls).
// lane = (sub, c): sub = lane>>4 is one of 4 parallel edge slots, c = lane&15
// is the 8-feature column segment; 4-row quads per slot, indices prefetched.
// POOL=true (layer 3): dot with Wl in-register, one fp32 atomic per node.
template <bool SCALE_SRC, bool POOL>
__launch_bounds__(128)
__global__ void k_gather_w(const ushort* __restrict__ hs, const int* __restrict__ rs,
                           const int* __restrict__ csr, const float* __restrict__ dinv,
                           const float* __restrict__ scale, const float* __restrict__ shift,
                           ushort* __restrict__ xout,
                           const int* __restrict__ bat, const float* __restrict__ invcnt,
                           const float* __restrict__ Wl, float* __restrict__ out2d) {
    __shared__ int nextn;
    const int tid = threadIdx.x;
    if (tid == 0) nextn = 0;
    __syncthreads();
    const int lane = tid & 63;
    const int sub = lane >> 4;
    const int c0 = (lane & 15) * 8;
    const int base = blockIdx.x * NODES_PER_BLK;

    for (int it = 0; it <= NODES_PER_BLK; ++it) {
        int myn = 0;
        if (lane == 0) myn = atomicAdd(&nextn, 1);
        myn = __shfl(myn, 0);
        if (myn >= NODES_PER_BLK) break;
        const int d = base + myn;

        const int e0 = rs[d], e1 = rs[d + 1];
        const float dd = dinv[d];

        float a0 = 0.f, a1 = 0.f, a2 = 0.f, a3 = 0.f,
              a4 = 0.f, a5 = 0.f, a6 = 0.f, a7 = 0.f;

        if (sub == 0) {   // self-loop term
            uint4 sv = *(const uint4*)(hs + (long)d * 128 + c0);
            float w = SCALE_SRC ? dd : 1.0f;
            a0 = w * bflo(sv.x); a1 = w * bfhi(sv.x);
            a2 = w * bflo(sv.y); a3 = w * bfhi(sv.y);
            a4 = w * bflo(sv.z); a5 = w * bfhi(sv.z);
            a6 = w * bflo(sv.w); a7 = w * bfhi(sv.w);
        }

        int j = e0 + sub;
        // ---- quad loop: rows j, j+4, j+8, j+12; next quad's indices prefetched ----
        int s0 = 0, s1 = 0, s2 = 0, s3 = 0;
        bool have = (j + 12 < e1);
        if (have) { s0 = csr[j]; s1 = csr[j + 4]; s2 = csr[j + 8]; s3 = csr[j + 12]; }
        while (have) {
            int jn = j + 16;
            bool nxt = (jn + 12 < e1);
            int n0 = 0, n1 = 0, n2 = 0, n3 = 0;
            if (nxt) { n0 = csr[jn]; n1 = csr[jn + 4]; n2 = csr[jn + 8]; n3 = csr[jn + 12]; }
            float w0 = 1.f, w1 = 1.f, w2 = 1.f, w3 = 1.f;
            if (SCALE_SRC) { w0 = dinv[s0]; w1 = dinv[s1]; w2 = dinv[s2]; w3 = dinv[s3]; }
            uint4 v0 = *(const uint4*)(hs + (long)s0 * 128 + c0);
            uint4 v1 = *(const uint4*)(hs + (long)s1 * 128 + c0);
            uint4 v2 = *(const uint4*)(hs + (long)s2 * 128 + c0);
            uint4 v3 = *(const uint4*)(hs + (long)s3 * 128 + c0);
            a0 += w0 * bflo(v0.x) + w1 * bflo(v1.x) + w2 * bflo(v2.x) + w3 * bflo(v3.x);
            a1 += w0 * bfhi(v0.x) + w1 * bfhi(v1.x) + w2 * bfhi(v2.x) + w3 * bfhi(v3.x);
            a2 += w0 * bflo(v0.y) + w1 * bflo(v1.y) + w2 * bflo(v2.y) + w3 * bflo(v3.y);
            a3 += w0 * bfhi(v0.y) + w1 * bfhi(v1.y) + w2 * bfhi(v2.y) + w3 * bfhi(v3.y);
            a4 += w0 * bflo(v0.z) + w1 * bflo(v1.z) + w2 * bflo(v2.z) + w3 * bflo(v3.z);
            a5 += w0 * bfhi(v0.z) + w1 * bfhi(v1.z) + w2 * bfhi(v2.z) + w3 * bfhi(v3.z);
            a6 += w0 * bflo(v0.w) + w1 * bflo(v1.w) + w2 * bflo(v2.w) + w3 * bflo(v3.w);
            a7 += w0 * bfhi(v0.w) + w1 * bfhi(v1.w) + w2 * bfhi(v2.w) + w3 * bfhi(v3.w);
            j = jn; s0 = n0; s1 = n1; s2 = n2; s3 = n3; have = nxt;
        }
        // ---- tail: up to 3 rows (j, j+4, j+8), all loads issued together ----
        if (j < e1) {
            bool b1 = (j + 4) < e1, b2 = (j + 8) < e1;
            int t0 = csr[j];
            int t1 = b1 ? csr[j + 4] : t0;
            int t2 = b2 ? csr[j + 8] : t0;
            float w0 = SCALE_SRC ? dinv[t0] : 1.f;
            float w1 = b1 ? (SCALE_SRC ? dinv[t1] : 1.f) : 0.f;
            float w2 = b2 ? (SCALE_SRC ? dinv[t2] : 1.f) : 0.f;
            uint4 v0 = *(const uint4*)(hs + (long)t0 * 128 + c0);
            uint4 v1 = *(const uint4*)(hs + (long)t1 * 128 + c0);
            uint4 v2 = *(const uint4*)(hs + (long)t2 * 128 + c0);
            a0 += w0 * bflo(v0.x) + w1 * bflo(v1.x) + w2 * bflo(v2.x);
            a1 += w0 * bfhi(v0.x) + w1 * bfhi(v1.x) + w2 * bfhi(v2.x);
            a2 += w0 * bflo(v0.y) + w1 * bflo(v1.y) + w2 * bflo(v2.y);
            a3 += w0 * bfhi(v0.y) + w1 * bfhi(v1.y) + w2 * bfhi(v2.y);
            a4 += w0 * bflo(v0.z) + w1 * bflo(v1.z) + w2 * bflo(v2.z);
            a5 += w0 * bfhi(v0.z) + w1 * bfhi(v1.z) + w2 * bfhi(v2.z);
            a6 += w0 * bflo(v0.w) + w1 * bflo(v1.w) + w2 * bflo(v2.w);
            a7 += w0 * bfhi(v0.w) + w1 * bfhi(v1.w) + w2 * bfhi(v2.w);
        }

        // reduce across the 4 edge slots (lanes differing in bits 4,5)
        a0 += __shfl_xor(a0, 16); a1 += __shfl_xor(a1, 16);
        a2 += __shfl_xor(a2, 16); a3 += __shfl_xor(a3, 16);
        a4 += __shfl_xor(a4, 16); a5 += __shfl_xor(a5, 16);
        a6 += __shfl_xor(a6, 16); a7 += __shfl_xor(a7, 16);
        a0 += __shfl_xor(a0, 32); a1 += __shfl_xor(a1, 32);
        a2 += __shfl_xor(a2, 32); a3 += __shfl_xor(a3, 32);
        a4 += __shfl_xor(a4, 32); a5 += __shfl_xor(a5, 32);
        a6 += __shfl_xor(a6, 32); a7 += __shfl_xor(a7, 32);

        float pd = 0.f;
        if (sub == 0) {
            float4 sca = *(const float4*)(scale + c0);
            float4 scb = *(const float4*)(scale + c0 + 4);
            float4 sha = *(const float4*)(shift + c0);
            float4 shb = *(const float4*)(shift + c0 + 4);
            float r0 = fmaxf(dd * a0 * sca.x + sha.x, 0.f);
            float r1 = fmaxf(dd * a1 * sca.y + sha.y, 0.f);
            float r2 = fmaxf(dd * a2 * sca.z + sha.z, 0.f);
            float r3 = fmaxf(dd * a3 * sca.w + sha.w, 0.f);
            float r4 = fmaxf(dd * a4 * scb.x + shb.x, 0.f);
            float r5 = fmaxf(dd * a5 * scb.y + shb.y, 0.f);
            float r6 = fmaxf(dd * a6 * scb.z + shb.z, 0.f);
            float r7 = fmaxf(dd * a7 * scb.w + shb.w, 0.f);
            if constexpr (POOL) {
                float4 wa = *(const float4*)(Wl + c0);
                float4 wb = *(const float4*)(Wl + c0 + 4);
                pd = r0 * wa.x + r1 * wa.y + r2 * wa.z + r3 * wa.w +
                     r4 * wb.x + r5 * wb.y + r6 * wb.z + r7 * wb.w;
            } else {
                uint4 o;
                o.x = (uint)f2bf(r0) | ((uint)f2bf(r1) << 16);
                o.y = (uint)f2bf(r2) | ((uint)f2bf(r3) << 16);
                o.z = (uint)f2bf(r4) | ((uint)f2bf(r5) << 16);
                o.w = (uint)f2bf(r6) | ((uint)f2bf(r7) << 16);
                *(uint4*)(xout + (long)d * 128 + c0) = o;
            }
        }
        if constexpr (POOL) {
            pd += __shfl_xor(pd, 1);
            pd += __shfl_xor(pd, 2);
            pd += __shfl_xor(pd, 4);
            pd += __shfl_xor(pd, 8);
            if (lane == 0) {
                int g = bat[d];
                atomicAdd(&out2d[g * 8 + (d & 7)], pd * invcnt[g]);
            }
        }
    }
}

// ---------------- finalize: out[g] = bl + sum of 8 slots ----------------
__global__ void k_final(const float* __restrict__ out2d, const float* __restrict__ bl,
                        float* __restrict__ out) {
    int g = blockIdx.x * 256 + threadIdx.x;
    if (g >= NG) return;
    float s = bl[0];
#pragma unroll
    for (int i = 0; i < 8; ++i) s += out2d[g * 8 + i];
    out[g] = s;
}

// ---------------- launch ----------------
extern "C" void kernel_launch(void* const* d_in, const int* in_sizes, int n_in,
                              void* d_out, int out_size, void* d_ws, size_t ws_size,
                              hipStream_t stream) {
    const float* x   = (const float*)d_in[0];
    const int*   ei  = (const int*)d_in[1];
    const int*   bat = (const int*)d_in[2];
    const float* W1  = (const float*)d_in[3];
    const float* b1  = (const float*)d_in[4];
    const float* g1  = (const float*)d_in[5];
    const float* be1 = (const float*)d_in[6];
    const float* m1  = (const float*)d_in[7];
    const float* v1  = (const float*)d_in[8];
    const float* W2  = (const float*)d_in[9];
    const float* b2  = (const float*)d_in[10];
    const float* g2  = (const float*)d_in[11];
    const float* be2 = (const float*)d_in[12];
    const float* m2  = (const float*)d_in[13];
    const float* v2  = (const float*)d_in[14];
    const float* W3  = (const float*)d_in[15];
    const float* b3  = (const float*)d_in[16];
    const float* g3  = (const float*)d_in[17];
    const float* be3 = (const float*)d_in[18];
    const float* m3  = (const float*)d_in[19];
    const float* v3  = (const float*)d_in[20];
    const float* Wl  = (const float*)d_in[21];
    const float* bl  = (const float*)d_in[22];
    float* out = (float*)d_out;

    const int* srcp = ei;        // edge_index[0]
    const int* dstp = ei + NE;   // edge_index[1]

    // ---- workspace layout ----
    char* ws = (char*)d_ws;
    size_t off = 0;
    auto alloc = [&](size_t bytes) { char* p = ws + off; off += (bytes + 255) & ~255ULL; return p; };
    float*  dinv     = (float*) alloc(NN * 4);
    int*    rs       = (int*)   alloc((NN + 1) * 4);
    int*    L        = (int*)   alloc((size_t)NBIN * NBLK_BIN * 4);   // block-bin table, 612 KB
    int*    binTot   = (int*)   alloc((NBIN + 1) * 4);
    int*    bin_ebase= (int*)   alloc((NBIN + 1) * 4);
    uint*   bpack    = (uint*)  alloc((size_t)NE * 4);   // 6.4 MB (bin-grouped edges)
    int*    csr      = (int*)   alloc((size_t)NE * 4);   // 6.4 MB
    float*  scale1 = (float*) alloc(HD * 4);
    float*  shift1 = (float*) alloc(HD * 4);
    float*  scale2 = (float*) alloc(HD * 4);
    float*  shift2 = (float*) alloc(HD * 4);
    float*  scale3 = (float*) alloc(HD * 4);
    float*  shift3 = (float*) alloc(HD * 4);
    float*  invcnt = (float*) alloc(NG * 4);
    float*  out2d  = (float*) alloc(NG * 8 * 4);
    ushort* Wt1    = (ushort*)alloc(128 * 128 * 2);    // 32 KB
    ushort* Wt2    = (ushort*)alloc(128 * 128 * 2);
    ushort* Wt3    = (ushort*)alloc(128 * 128 * 2);
    ushort* hs     = (ushort*)alloc((size_t)NN * HD * 2);   // 25.6 MB
    ushort* xbuf   = (ushort*)alloc((size_t)NN * HD * 2);   // 25.6 MB

    // ---- prep: W transpose + BN affine + graph inv-counts (one launch) ----
    k_prep_all<<<197, 256, 0, stream>>>(W1, W2, W3, Wt1, Wt2, Wt3,
                                        b1, g1, be1, m1, v1, b2, g2, be2, m2, v2,
                                        b3, g3, be3, m3, v3,
                                        scale1, shift1, scale2, shift2, scale3, shift3,
                                        bat, invcnt, out2d);

    // ---- fused: GEMM1 (unscaled) || bin histogram (LDS only) ----
    k_fused1<<<GEMM_BLOCKS + NBLK_BIN, 256, 0, stream>>>(x, Wt1, hs, dstp, L);

    // ---- CSR build: parallel scans, bin-scatter, per-bin CSR (+rs, dinv) ----
    k_scanA<<<NBIN, 512, 0, stream>>>(L, binTot);
    k_scanB<<<1, 512, 0, stream>>>(binTot, bin_ebase, rs);
    k_binscatter<<<NBLK_BIN, 256, 0, stream>>>(srcp, dstp, L, bin_ebase, bpack);
    k_bincsr<<<NBIN, 256, 0, stream>>>(bpack, bin_ebase, rs, dinv, csr);

    // ---- layer 1 gather (applies dinv[s] and dinv[d]) ----
    k_gather_w<true, false><<<GATH_BLOCKS, 128, 0, stream>>>(
        hs, rs, csr, dinv, scale1, shift1, xbuf, nullptr, nullptr, nullptr, nullptr);
    // ---- layer 2 ----
    k_gemm_l23<<<GEMM_BLOCKS, 256, 0, stream>>>(xbuf, Wt2, dinv, hs);
    k_gather_w<false, false><<<GATH_BLOCKS, 128, 0, stream>>>(
        hs, rs, csr, dinv, scale2, shift2, xbuf, nullptr, nullptr, nullptr, nullptr);
    // ---- layer 3 ----
    k_gemm_l23<<<GEMM_BLOCKS, 256, 0, stream>>>(xbuf, Wt3, dinv, hs);
    k_gather_w<false, true><<<GATH_BLOCKS, 128, 0, stream>>>(
        hs, rs, csr, dinv, scale3, shift3, nullptr, bat, invcnt, Wl, out2d);

    // ---- finalize ----
    k_final<<<2, 256, 0, stream>>>(out2d, bl, out);
}